// Round 9
// baseline (18628.680 us; speedup 1.0000x reference)
//
#include <hip/hip_runtime.h>
#include <hip/hip_fp16.h>
#include <cstddef>

#define Pn 81
#define En 256
#define Hn 4096
#define H4 16384          // 4*Hn
#define KSPLIT 64
#define KC (Hn / KSPLIT)  // 64
#define CG 8              // column groups: 8 panels x 2048 f32 cols
#define TT 16             // t-tile for X projection
#define NBLK (KSPLIT * CG)   // 512 persistent blocks

// Tiled Mh layout: unit (kc,cgp) owns a contiguous 256KB slice of uint4 (8 halves).
// uint4 index of (local row k 0..63, col8 0..255) = slice(kc,cgp) + k*256 + col8.
__device__ __forceinline__ size_t mt_slice(int kc, int cgp) {
    return ((size_t)(kc * CG + cgp)) * (KC * 256);
}

// ---------------- X[t] = h_enc[t] @ W[:E] + b   (Pn x H4) ----------------
__global__ __launch_bounds__(256) void xproj_kernel(const float* __restrict__ henc,
                                                    const float* __restrict__ W,
                                                    const float* __restrict__ bias,
                                                    float* __restrict__ X) {
    int col = blockIdx.x * 256 + threadIdx.x;
    int t0  = blockIdx.y * TT;
    __shared__ float hs[TT][En];
    for (int r = threadIdx.x; r < TT * En; r += 256) {
        int tt = r >> 8;
        int e  = r & (En - 1);
        hs[tt][e] = (t0 + tt < Pn) ? henc[(size_t)(t0 + tt) * En + e] : 0.f;
    }
    __syncthreads();
    float acc[TT];
    float bc = bias[col];
#pragma unroll
    for (int tt = 0; tt < TT; ++tt) acc[tt] = bc;
    for (int e = 0; e < En; ++e) {
        float w = W[(size_t)e * H4 + col];
#pragma unroll
        for (int tt = 0; tt < TT; ++tt) acc[tt] += hs[tt][e] * w;
    }
    int nt = Pn - t0; if (nt > TT) nt = TT;
    for (int tt = 0; tt < nt; ++tt) X[(size_t)(t0 + tt) * H4 + col] = acc[tt];
}

// ---------------- init: orders[0] = h0, c0 = 0 (fallback path) ----------------
__global__ __launch_bounds__(256) void init_kernel(const float* __restrict__ h0,
                                                   float* __restrict__ orders,
                                                   float* __restrict__ c0) {
    int i = blockIdx.x * 256 + threadIdx.x;
    orders[i] = h0[i];
    c0[i] = 0.f;
}

// ------------- convert only: Mt = tiled f16(W[E:]+U).  2048 blocks x 256 thr -------------
__global__ __launch_bounds__(256) void fuse_convert_kernel(const float* __restrict__ W,
                                                           const float* __restrict__ U,
                                                           __half* __restrict__ Mt) {
    const int q   = blockIdx.x & 3;          // quarter: local rows q*16..+16
    const int cgp = blockIdx.x >> 2;         // 0..7
    const int kc  = blockIdx.y;              // 0..63
    const int tid = threadIdx.x;             // 0..255
    const int c0  = cgp * 2048 + tid * 8;    // f32 column base
    uint4* M8 = (uint4*)Mt;
    const size_t slice = mt_slice(kc, cgp);
#pragma unroll 4
    for (int k = 0; k < 16; ++k) {
        const int kl   = q * 16 + k;
        const int krow = kc * KC + kl;
        const float4* Wp = (const float4*)(W + (size_t)(En + krow) * H4 + c0);
        const float4* Up = (const float4*)(U + (size_t)krow * H4 + c0);
        float4 w0 = Wp[0], w1 = Wp[1];
        float4 u0 = Up[0], u1 = Up[1];
        alignas(16) __half2 hm[4];
        hm[0] = __floats2half2_rn(w0.x + u0.x, w0.y + u0.y);
        hm[1] = __floats2half2_rn(w0.z + u0.z, w0.w + u0.w);
        hm[2] = __floats2half2_rn(w1.x + u1.x, w1.y + u1.y);
        hm[3] = __floats2half2_rn(w1.z + u1.z, w1.w + u1.w);
        M8[slice + (size_t)kl * 256 + tid] = *(const uint4*)hm;
    }
}

// ---------------- custom grid barrier (flags + generation) ----------------
__device__ __forceinline__ void gbar(unsigned* flags, unsigned* gen,
                                     int bid, int tid, unsigned target) {
    __threadfence();            // agent-scope release of this thread's stores
    __syncthreads();
    if (bid == 0) {
        if (tid > 0 && tid < NBLK) {
            while (__hip_atomic_load(&flags[tid], __ATOMIC_ACQUIRE,
                                     __HIP_MEMORY_SCOPE_AGENT) < target)
                __builtin_amdgcn_s_sleep(2);
        }
        __syncthreads();
        if (tid == 0)
            __hip_atomic_store(gen, target, __ATOMIC_RELEASE, __HIP_MEMORY_SCOPE_AGENT);
    } else {
        if (tid == 0) {
            __hip_atomic_store(&flags[bid], target, __ATOMIC_RELEASE,
                               __HIP_MEMORY_SCOPE_AGENT);
            while (__hip_atomic_load(gen, __ATOMIC_ACQUIRE,
                                     __HIP_MEMORY_SCOPE_AGENT) < target)
                __builtin_amdgcn_s_sleep(2);
        }
        __syncthreads();
    }
}

// ---------------- persistent kernel: steps t=0..80, custom barrier ----------------
__global__ __launch_bounds__(512, 4) void persist_kernel(const __half* __restrict__ Mt,
                                                         const float* __restrict__ X,
                                                         float* __restrict__ zp0,
                                                         float* __restrict__ zp1,
                                                         float* __restrict__ orders,
                                                         const float* __restrict__ h0,
                                                         unsigned* flags,
                                                         unsigned* gen) {
    const int bid  = blockIdx.x;
    const int kc   = bid >> 3;
    const int cgp  = bid & 7;
    const int tid  = threadIdx.x;
    const int half = tid >> 8;                  // 0 or 1
    const int t256 = tid & 255;
    const int lane = tid & 63;
    const int g    = tid >> 6;                  // 0..7
    const int j    = kc * KC + lane;
    const uint4* M8 = (const uint4*)Mt;
    const size_t slice = mt_slice(kc, cgp);

    __shared__ float hs[KC];
    __shared__ float c_l[KC];
    __shared__ float red[4][8][64];
    __shared__ float accbuf[256][9];

    if (tid < KC) c_l[tid] = 0.f;
    if (cgp == 0 && g == 0) orders[j] = h0[j];   // orders[0] = h0

    float* zprev = zp1;   // unused at t=0
    float* zcur  = zp0;

    // prologue prefetch for t=0 stream
    uint4 buf[16];
#pragma unroll
    for (int p = 0; p < 16; ++p)
        buf[p] = M8[slice + (size_t)(half * 32 + p) * 256 + t256];

    for (int t = 0; t < Pn; ++t) {
        if (t == 0) {
            if (tid < KC) hs[tid] = h0[kc * KC + tid];
        } else {
            // ---- gate: h_t, c_t from zprev + X[t-1] + LDS c ----
            float s0 = 0.f, s1 = 0.f, s2 = 0.f, s3 = 0.f;
            for (int ks = g; ks < KSPLIT; ks += 8) {
                const float* zpp = zprev + (size_t)ks * H4;
                s0 += zpp[j];
                s1 += zpp[j + Hn];
                s2 += zpp[j + 2 * Hn];
                s3 += zpp[j + 3 * Hn];
            }
            red[0][g][lane] = s0;
            red[1][g][lane] = s1;
            red[2][g][lane] = s2;
            red[3][g][lane] = s3;
            __syncthreads();
            if (g == 0) {
                const float* Xt = X + (size_t)(t - 1) * H4;
                float zi = Xt[j], zf = Xt[j + Hn], zg = Xt[j + 2 * Hn], zo = Xt[j + 3 * Hn];
#pragma unroll
                for (int g2 = 0; g2 < 8; ++g2) {
                    zi += red[0][g2][lane];
                    zf += red[1][g2][lane];
                    zg += red[2][g2][lane];
                    zo += red[3][g2][lane];
                }
                float gi = 1.f / (1.f + __expf(-zi));
                float gf = 1.f / (1.f + __expf(-zf));
                float go = 1.f / (1.f + __expf(-zo));
                float cn = gf * c_l[lane] + gi * zg;   // candidate activation = identity
                float hn = go * cn;                    // output activation = identity
                if (cgp == 0) orders[(size_t)t * Hn + j] = hn;
                c_l[lane] = cn;
                hs[lane] = hn;
            }
        }
        if (t == Pn - 1) break;    // t=80: gate only (orders[80] written)
        __syncthreads();

        // ---- stream: zcur partials = h_t[kc range] @ Mt slice ----
        float acc[8];
#pragma unroll
        for (int p = 0; p < 8; ++p) acc[p] = 0.f;
#pragma unroll
        for (int k = 0; k < 32; ++k) {
            uint4 raw;
            if (k < 16) raw = buf[k];
            else        raw = M8[slice + (size_t)(half * 32 + k) * 256 + t256];
            float hk = hs[half * 32 + k];
            const __half2* hp = (const __half2*)&raw;
#pragma unroll
            for (int q = 0; q < 4; ++q) {
                float2 f = __half22float2(hp[q]);
                acc[2 * q]     += hk * f.x;
                acc[2 * q + 1] += hk * f.y;
            }
        }
        if (half == 1) {
#pragma unroll
            for (int p = 0; p < 8; ++p) accbuf[t256][p] = acc[p];
        }
        __syncthreads();
        if (half == 0) {
#pragma unroll
            for (int p = 0; p < 8; ++p) acc[p] += accbuf[t256][p];
            float4* zw = (float4*)(zcur + (size_t)kc * H4 + (size_t)(cgp * 256 + t256) * 8);
            zw[0] = make_float4(acc[0], acc[1], acc[2], acc[3]);
            zw[1] = make_float4(acc[4], acc[5], acc[6], acc[7]);
        }

        // prefetch next step's head while the barrier drains/spins
        if (t + 1 < Pn - 1) {
#pragma unroll
            for (int p = 0; p < 16; ++p)
                buf[p] = M8[slice + (size_t)(half * 32 + p) * 256 + t256];
        }

        gbar(flags, gen, bid, tid, (unsigned)(t + 1));
        float* tz = zcur; zcur = zprev; zprev = tz;
    }
}

// ---------------- per-step kernel (fallback): t=0 uses h0, t>=1 gates ----------------
__global__ __launch_bounds__(512) void step_kernel(const __half* __restrict__ Mt,
                                                   const float* __restrict__ X,
                                                   const float* __restrict__ zprev,
                                                   float* __restrict__ zcur,
                                                   const float* __restrict__ cprev,
                                                   float* __restrict__ ccur,
                                                   float* __restrict__ orders,
                                                   const float* __restrict__ h0,
                                                   int t) {
    const int cgp  = blockIdx.x;
    const int kc   = blockIdx.y;
    const int tid  = threadIdx.x;
    const int half = tid >> 8;
    const int t256 = tid & 255;
    const uint4* M8 = (const uint4*)Mt;
    const size_t slice = mt_slice(kc, cgp);

    uint4 buf[8];
#pragma unroll
    for (int p = 0; p < 8; ++p)
        buf[p] = M8[slice + (size_t)(half * 32 + p) * 256 + t256];

    __shared__ float hs[KC];
    if (t == 0) {
        if (tid < KC) hs[tid] = h0[kc * KC + tid];
    } else {
        const int lane = tid & 63;
        const int g    = tid >> 6;
        const int j    = kc * KC + lane;
        float s0 = 0.f, s1 = 0.f, s2 = 0.f, s3 = 0.f;
        for (int ks = g; ks < KSPLIT; ks += 8) {
            const float* zpp = zprev + (size_t)ks * H4;
            s0 += zpp[j];
            s1 += zpp[j + Hn];
            s2 += zpp[j + 2 * Hn];
            s3 += zpp[j + 3 * Hn];
        }
        __shared__ float red[4][8][64];
        red[0][g][lane] = s0;
        red[1][g][lane] = s1;
        red[2][g][lane] = s2;
        red[3][g][lane] = s3;
        __syncthreads();
        if (g == 0) {
            const float* Xt = X + (size_t)(t - 1) * H4;
            float zi = Xt[j], zf = Xt[j + Hn], zg = Xt[j + 2 * Hn], zo = Xt[j + 3 * Hn];
#pragma unroll
            for (int g2 = 0; g2 < 8; ++g2) {
                zi += red[0][g2][lane];
                zf += red[1][g2][lane];
                zg += red[2][g2][lane];
                zo += red[3][g2][lane];
            }
            float gi = 1.f / (1.f + __expf(-zi));
            float gf = 1.f / (1.f + __expf(-zf));
            float go = 1.f / (1.f + __expf(-zo));
            float cn = gf * cprev[j] + gi * zg;
            float hn = go * cn;
            if (cgp == 0) {
                orders[(size_t)t * Hn + j] = hn;
                ccur[j] = cn;
            }
            hs[lane] = hn;
        }
    }
    __syncthreads();

    float acc[8];
#pragma unroll
    for (int p = 0; p < 8; ++p) acc[p] = 0.f;
#pragma unroll
    for (int k = 0; k < 32; ++k) {
        uint4 raw;
        if (k < 8) raw = buf[k];
        else       raw = M8[slice + (size_t)(half * 32 + k) * 256 + t256];
        float hk = hs[half * 32 + k];
        const __half2* hp = (const __half2*)&raw;
#pragma unroll
        for (int q = 0; q < 4; ++q) {
            float2 f = __half22float2(hp[q]);
            acc[2 * q]     += hk * f.x;
            acc[2 * q + 1] += hk * f.y;
        }
    }
    __shared__ float accbuf[256][9];
    if (half == 1) {
#pragma unroll
        for (int p = 0; p < 8; ++p) accbuf[t256][p] = acc[p];
    }
    __syncthreads();
    if (half == 0) {
#pragma unroll
        for (int p = 0; p < 8; ++p) acc[p] += accbuf[t256][p];
        float4* zw = (float4*)(zcur + (size_t)kc * H4 + (size_t)(cgp * 256 + t256) * 8);
        zw[0] = make_float4(acc[0], acc[1], acc[2], acc[3]);
        zw[1] = make_float4(acc[4], acc[5], acc[6], acc[7]);
    }
}

// ---------------- epilogue for fallback: orders[80] (gate only) ----------------
__global__ __launch_bounds__(256) void final_gate_kernel(const float* __restrict__ zprev,
                                                         const float* __restrict__ X,
                                                         const float* __restrict__ cprev,
                                                         float* __restrict__ orders) {
    const int lane = threadIdx.x & 63;
    const int g    = threadIdx.x >> 6;
    const int j    = blockIdx.x * 64 + lane;
    float s0 = 0.f, s1 = 0.f, s2 = 0.f, s3 = 0.f;
    for (int ks = g; ks < KSPLIT; ks += 4) {
        const float* zp = zprev + (size_t)ks * H4;
        s0 += zp[j];
        s1 += zp[j + Hn];
        s2 += zp[j + 2 * Hn];
        s3 += zp[j + 3 * Hn];
    }
    __shared__ float red[4][4][64];
    red[0][g][lane] = s0;
    red[1][g][lane] = s1;
    red[2][g][lane] = s2;
    red[3][g][lane] = s3;
    __syncthreads();
    if (g == 0) {
        const float* Xt = X + (size_t)(Pn - 2) * H4;   // X[79]
        float zi = Xt[j]          + red[0][0][lane] + red[0][1][lane] + red[0][2][lane] + red[0][3][lane];
        float zf = Xt[j + Hn]     + red[1][0][lane] + red[1][1][lane] + red[1][2][lane] + red[1][3][lane];
        float zg = Xt[j + 2 * Hn] + red[2][0][lane] + red[2][1][lane] + red[2][2][lane] + red[2][3][lane];
        float zo = Xt[j + 3 * Hn] + red[3][0][lane] + red[3][1][lane] + red[3][2][lane] + red[3][3][lane];
        float gi = 1.f / (1.f + __expf(-zi));
        float gf = 1.f / (1.f + __expf(-zf));
        float go = 1.f / (1.f + __expf(-zo));
        float cn = gf * cprev[j] + gi * zg;
        orders[(size_t)(Pn - 1) * Hn + j] = go * cn;
    }
}

// ================= fallback path (ws too small): f32, separate kernels =================
__global__ __launch_bounds__(256) void fb_init_kernel(const float* __restrict__ h0,
                                                      float* __restrict__ h,
                                                      float* __restrict__ c) {
    int i = blockIdx.x * 256 + threadIdx.x;
    h[i] = h0[i];
    c[i] = 0.f;
}

__global__ __launch_bounds__(256) void matvec2_kernel(const float* __restrict__ Wh,
                                                      const float* __restrict__ U,
                                                      const float* __restrict__ h,
                                                      float* __restrict__ zpart) {
    int col4 = blockIdx.x * 256 + threadIdx.x;
    int k0   = blockIdx.y * KC;
    __shared__ float hs[KC];
    if (threadIdx.x < KC) hs[threadIdx.x] = h[k0 + threadIdx.x];
    __syncthreads();
    const float4* W4 = (const float4*)Wh;
    const float4* U4 = (const float4*)U;
    size_t base = (size_t)k0 * (H4 / 4) + col4;
    float4 acc; acc.x = acc.y = acc.z = acc.w = 0.f;
#pragma unroll 2
    for (int k = 0; k < KC; ++k) {
        size_t idx = base + (size_t)k * (H4 / 4);
        float4 w = W4[idx];
        float4 u = U4[idx];
        float hk = hs[k];
        acc.x += hk * (w.x + u.x); acc.y += hk * (w.y + u.y);
        acc.z += hk * (w.z + u.z); acc.w += hk * (w.w + u.w);
    }
    ((float4*)zpart)[(size_t)blockIdx.y * (H4 / 4) + col4] = acc;
}

__global__ __launch_bounds__(256) void gate_kernel(const float* __restrict__ zpart,
                                                   const float* __restrict__ X,
                                                   float* __restrict__ h,
                                                   float* __restrict__ c,
                                                   float* __restrict__ orders,
                                                   int t) {
    int lane = threadIdx.x & 63;
    int g    = threadIdx.x >> 6;
    int j    = blockIdx.x * 64 + lane;
    float s0 = 0.f, s1 = 0.f, s2 = 0.f, s3 = 0.f;
    for (int ks = g; ks < KSPLIT; ks += 4) {
        const float* zp = zpart + (size_t)ks * H4;
        s0 += zp[j];
        s1 += zp[j + Hn];
        s2 += zp[j + 2 * Hn];
        s3 += zp[j + 3 * Hn];
    }
    __shared__ float red[4][4][64];
    red[0][g][lane] = s0;
    red[1][g][lane] = s1;
    red[2][g][lane] = s2;
    red[3][g][lane] = s3;
    __syncthreads();
    if (g == 0) {
        const float* Xt = X + (size_t)t * H4;
        float zi = Xt[j]          + red[0][0][lane] + red[0][1][lane] + red[0][2][lane] + red[0][3][lane];
        float zf = Xt[j + Hn]     + red[1][0][lane] + red[1][1][lane] + red[1][2][lane] + red[1][3][lane];
        float zg = Xt[j + 2 * Hn] + red[2][0][lane] + red[2][1][lane] + red[2][2][lane] + red[2][3][lane];
        float zo = Xt[j + 3 * Hn] + red[3][0][lane] + red[3][1][lane] + red[3][2][lane] + red[3][3][lane];
        float gi = 1.f / (1.f + __expf(-zi));
        float gf = 1.f / (1.f + __expf(-zf));
        float go = 1.f / (1.f + __expf(-zo));
        float cn = gf * c[j] + gi * zg;
        float ho = h[j];
        float hn = go * cn;
        orders[(size_t)t * Hn + j] = ho;
        h[j] = hn;
        c[j] = cn;
    }
}

extern "C" void kernel_launch(void* const* d_in, const int* in_sizes, int n_in,
                              void* d_out, int out_size, void* d_ws, size_t ws_size,
                              hipStream_t stream) {
    const float* henc = (const float*)d_in[0];
    const float* h0   = (const float*)d_in[1];
    const float* W    = (const float*)d_in[2];
    const float* U    = (const float*)d_in[3];
    const float* bias = (const float*)d_in[4];
    float* out = (float*)d_out;

    const size_t needM = (size_t)Hn * H4 * sizeof(__half);    // 134 MB fp16 (tiled)
    const size_t needX = (size_t)Pn * H4 * sizeof(float);     // 5.3 MB
    const size_t needZ = (size_t)KSPLIT * H4 * sizeof(float); // 4.2 MB (x2)
    const size_t needC = (size_t)Hn * sizeof(float);          // 16 KB (x2)
    const size_t needB = 4096;                                // barrier flags + gen

    char* ws = (char*)d_ws;
    const bool fused = ws_size >= needM + needX + 2 * needZ + 2 * needC + needB;

    if (fused) {
        __half* Mt  = (__half*)ws;
        float*  X   = (float*)(ws + needM);
        float*  z0  = (float*)(ws + needM + needX);
        float*  z1  = (float*)(ws + needM + needX + needZ);
        float*  cb0 = (float*)(ws + needM + needX + 2 * needZ);
        float*  cb1 = cb0 + Hn;
        unsigned* bar = (unsigned*)(ws + needM + needX + 2 * needZ + 2 * needC);
        unsigned* flags = bar;          // [512]
        unsigned* gen   = bar + NBLK;   // [1]

        xproj_kernel<<<dim3(H4 / 256, (Pn + TT - 1) / TT), 256, 0, stream>>>(henc, W, bias, X);
        fuse_convert_kernel<<<dim3(CG * 4, KSPLIT), 256, 0, stream>>>(W, U, Mt);
        hipMemsetAsync(bar, 0, needB, stream);

        const __half* MtA = Mt;
        const float*  XA  = X;
        float* z0A = z0;
        float* z1A = z1;
        float* outA = out;
        const float* h0A = h0;
        unsigned* flagsA = flags;
        unsigned* genA   = gen;
        void* pargs[] = {(void*)&MtA, (void*)&XA, (void*)&z0A, (void*)&z1A,
                         (void*)&outA, (void*)&h0A, (void*)&flagsA, (void*)&genA};
        hipError_t cerr = hipLaunchCooperativeKernel(
            persist_kernel, dim3(NBLK), dim3(512), pargs, 0u, stream);
        if (cerr != hipSuccess) {
            (void)hipGetLastError();   // clear sticky error, use per-step fallback
            init_kernel<<<dim3(Hn / 256), 256, 0, stream>>>(h0, out, cb0);
            float* zp[2] = {z0, z1};
            float* cb[2] = {cb0, cb1};
            for (int t = 0; t < Pn - 1; ++t) {   // t streams into zp[t&1]
                step_kernel<<<dim3(CG, KSPLIT), 512, 0, stream>>>(
                    Mt, X, zp[(t + 1) & 1], zp[t & 1],
                    cb[(t + 1) & 1], cb[t & 1], out, h0, t);
            }
            final_gate_kernel<<<dim3(Hn / 64), 256, 0, stream>>>(zp[1], X, cb[1], out);
        }
    } else {
        float* X     = (float*)ws;
        float* zpart = (float*)(ws + needX);
        float* h     = (float*)(ws + needX + needZ);
        float* c     = h + Hn;

        xproj_kernel<<<dim3(H4 / 256, (Pn + TT - 1) / TT), 256, 0, stream>>>(henc, W, bias, X);
        fb_init_kernel<<<dim3(Hn / 256), 256, 0, stream>>>(h0, h, c);
        for (int t = 0; t < Pn; ++t) {
            matvec2_kernel<<<dim3(H4 / 4 / 256, KSPLIT), 256, 0, stream>>>(
                W + (size_t)En * H4, U, h, zpart);
            gate_kernel<<<dim3(Hn / 64), 256, 0, stream>>>(zpart, X, h, c, out, t);
        }
    }
}

// Round 10
// 2029.838 us; speedup vs baseline: 9.1774x; 9.1774x over previous
//
#include <hip/hip_runtime.h>
#include <hip/hip_fp16.h>
#include <cstddef>

#define Pn 81
#define En 256
#define Hn 4096
#define H4 16384          // 4*Hn
#define KSPLIT 32
#define KC (Hn / KSPLIT)  // 128 rows per k-chunk
#define CG 8              // column groups: 8 panels x 2048 f32 cols
#define TT 16             // t-tile for X projection

// Tiled Mh layout: unit (kc,cgp) owns a contiguous 512KB slice of uint4 (8 halves each).
// uint4 index of (local row k 0..127, col8 0..255) = slice(kc,cgp) + k*256 + col8.
__device__ __forceinline__ size_t mt_slice(int kc, int cgp) {
    return ((size_t)(kc * CG + cgp)) * ((size_t)KC * 256);
}

// ---------------- X[t] = h_enc[t] @ W[:E] + b   (Pn x H4) ----------------
__global__ __launch_bounds__(256) void xproj_kernel(const float* __restrict__ henc,
                                                    const float* __restrict__ W,
                                                    const float* __restrict__ bias,
                                                    float* __restrict__ X) {
    int col = blockIdx.x * 256 + threadIdx.x;
    int t0  = blockIdx.y * TT;
    __shared__ float hs[TT][En];
    for (int r = threadIdx.x; r < TT * En; r += 256) {
        int tt = r >> 8;
        int e  = r & (En - 1);
        hs[tt][e] = (t0 + tt < Pn) ? henc[(size_t)(t0 + tt) * En + e] : 0.f;
    }
    __syncthreads();
    float acc[TT];
    float bc = bias[col];
#pragma unroll
    for (int tt = 0; tt < TT; ++tt) acc[tt] = bc;
    for (int e = 0; e < En; ++e) {
        float w = W[(size_t)e * H4 + col];
#pragma unroll
        for (int tt = 0; tt < TT; ++tt) acc[tt] += hs[tt][e] * w;
    }
    int nt = Pn - t0; if (nt > TT) nt = TT;
    for (int tt = 0; tt < nt; ++tt) X[(size_t)(t0 + tt) * H4 + col] = acc[tt];
}

// ---------------- init: orders[0] = h0, c0 = 0 ----------------
__global__ __launch_bounds__(256) void init_kernel(const float* __restrict__ h0,
                                                   float* __restrict__ orders,
                                                   float* __restrict__ c0) {
    int i = blockIdx.x * 256 + threadIdx.x;
    orders[i] = h0[i];
    c0[i] = 0.f;
}

// ------------- convert only: Mt = tiled f16(W[E:]+U).  2048 blocks x 256 thr -------------
__global__ __launch_bounds__(256) void fuse_convert_kernel(const float* __restrict__ W,
                                                           const float* __restrict__ U,
                                                           __half* __restrict__ Mt) {
    const int q   = blockIdx.x & 7;          // eighth: local rows q*16..+16 (of 128)
    const int cgp = blockIdx.x >> 3;         // 0..7
    const int kc  = blockIdx.y;              // 0..31
    const int tid = threadIdx.x;             // 0..255
    const int c0  = cgp * 2048 + tid * 8;    // f32 column base
    uint4* M8 = (uint4*)Mt;
    const size_t slice = mt_slice(kc, cgp);
#pragma unroll 4
    for (int k = 0; k < 16; ++k) {
        const int kl   = q * 16 + k;         // local row 0..127
        const int krow = kc * KC + kl;
        const float4* Wp = (const float4*)(W + (size_t)(En + krow) * H4 + c0);
        const float4* Up = (const float4*)(U + (size_t)krow * H4 + c0);
        float4 w0 = Wp[0], w1 = Wp[1];
        float4 u0 = Up[0], u1 = Up[1];
        alignas(16) __half2 hm[4];
        hm[0] = __floats2half2_rn(w0.x + u0.x, w0.y + u0.y);
        hm[1] = __floats2half2_rn(w0.z + u0.z, w0.w + u0.w);
        hm[2] = __floats2half2_rn(w1.x + u1.x, w1.y + u1.y);
        hm[3] = __floats2half2_rn(w1.z + u1.z, w1.w + u1.w);
        M8[slice + (size_t)kl * 256 + tid] = *(const uint4*)hm;
    }
}

// ---------------- step t: gate (h_t from zprev, skipped at t=0) + stream (zcur) ----------
// grid (CG=8, KSPLIT=32), 1024 threads (16 waves/CU, 1 block/CU).
// Gate: 8 groups x 128 lanes split the 32-slice ks-reduction (64KB/block, 16MB/step grid-wide).
// Stream: 4 quarter-groups x 256 cols cover the 128-row k-range; 8-deep prefetch; LDS merge.
__global__ __launch_bounds__(1024) void step_kernel(const __half* __restrict__ Mt,
                                                    const float* __restrict__ X,
                                                    const float* __restrict__ zprev,
                                                    float* __restrict__ zcur,
                                                    const float* __restrict__ cprev,
                                                    float* __restrict__ ccur,
                                                    float* __restrict__ orders,
                                                    const float* __restrict__ h0,
                                                    int t) {
    const int cgp  = blockIdx.x;                 // 0..7
    const int kc   = blockIdx.y;                 // 0..31
    const int tid  = threadIdx.x;
    const int half = tid >> 8;                   // 0..3 (row quarter)
    const int t256 = tid & 255;                  // col8 index
    const uint4* M8 = (const uint4*)Mt;
    const size_t slice = mt_slice(kc, cgp);

    // ---- prefetch first 8 of this thread's 32 row-reads ----
    uint4 buf[8];
#pragma unroll
    for (int p = 0; p < 8; ++p)
        buf[p] = M8[slice + (size_t)(half * 32 + p) * 256 + t256];

    __shared__ float hs[KC];
    if (t == 0) {
        if (tid < KC) hs[tid] = h0[kc * KC + tid];
    } else {
        const int lane = tid & 127;              // row within chunk
        const int g    = tid >> 7;               // 0..7
        const int j    = kc * KC + lane;
        float s0 = 0.f, s1 = 0.f, s2 = 0.f, s3 = 0.f;
#pragma unroll
        for (int ks = g; ks < KSPLIT; ks += 8) {
            const float* zpp = zprev + (size_t)ks * H4;
            s0 += zpp[j];
            s1 += zpp[j + Hn];
            s2 += zpp[j + 2 * Hn];
            s3 += zpp[j + 3 * Hn];
        }
        __shared__ float red[4][8][KC];
        red[0][g][lane] = s0;
        red[1][g][lane] = s1;
        red[2][g][lane] = s2;
        red[3][g][lane] = s3;
        __syncthreads();
        if (g == 0) {
            const float* Xt = X + (size_t)(t - 1) * H4;
            float zi = Xt[j], zf = Xt[j + Hn], zg = Xt[j + 2 * Hn], zo = Xt[j + 3 * Hn];
#pragma unroll
            for (int g2 = 0; g2 < 8; ++g2) {
                zi += red[0][g2][lane];
                zf += red[1][g2][lane];
                zg += red[2][g2][lane];
                zo += red[3][g2][lane];
            }
            float gi = 1.f / (1.f + __expf(-zi));
            float gf = 1.f / (1.f + __expf(-zf));
            float go = 1.f / (1.f + __expf(-zo));
            float cn = gf * cprev[j] + gi * zg;   // candidate activation = identity
            float hn = go * cn;                   // output activation = identity
            if (cgp == 0) {
                orders[(size_t)t * Hn + j] = hn;  // orders[t] = h_t
                ccur[j] = cn;
            }
            hs[lane] = hn;
        }
    }
    __syncthreads();

    // ---- stream: zcur[kc][cgp cols] += over this block's 128-row chunk ----
    float acc[8];
#pragma unroll
    for (int p = 0; p < 8; ++p) acc[p] = 0.f;
#pragma unroll
    for (int k = 0; k < 32; ++k) {
        uint4 raw;
        if (k < 8) raw = buf[k];
        else       raw = M8[slice + (size_t)(half * 32 + k) * 256 + t256];
        float hk = hs[half * 32 + k];
        const __half2* hp = (const __half2*)&raw;
#pragma unroll
        for (int q = 0; q < 4; ++q) {
            float2 f = __half22float2(hp[q]);
            acc[2 * q]     += hk * f.x;
            acc[2 * q + 1] += hk * f.y;
        }
    }
    __shared__ float accbuf[3][256][9];   // quarters 1..3 park partials (+1 pad)
    if (half != 0) {
#pragma unroll
        for (int p = 0; p < 8; ++p) accbuf[half - 1][t256][p] = acc[p];
    }
    __syncthreads();
    if (half == 0) {
#pragma unroll
        for (int p = 0; p < 8; ++p)
            acc[p] += accbuf[0][t256][p] + accbuf[1][t256][p] + accbuf[2][t256][p];
        float4* zw = (float4*)(zcur + (size_t)kc * H4 + (size_t)(cgp * 256 + t256) * 8);
        zw[0] = make_float4(acc[0], acc[1], acc[2], acc[3]);
        zw[1] = make_float4(acc[4], acc[5], acc[6], acc[7]);
    }
}

// ---------------- epilogue: orders[80] = h_80 (gate only, no matvec) ----------------
__global__ __launch_bounds__(256) void final_gate_kernel(const float* __restrict__ zprev,
                                                         const float* __restrict__ X,
                                                         const float* __restrict__ cprev,
                                                         float* __restrict__ orders) {
    const int lane = threadIdx.x & 63;
    const int g    = threadIdx.x >> 6;           // 0..3
    const int j    = blockIdx.x * 64 + lane;
    float s0 = 0.f, s1 = 0.f, s2 = 0.f, s3 = 0.f;
#pragma unroll
    for (int ks = g; ks < KSPLIT; ks += 4) {
        const float* zp = zprev + (size_t)ks * H4;
        s0 += zp[j];
        s1 += zp[j + Hn];
        s2 += zp[j + 2 * Hn];
        s3 += zp[j + 3 * Hn];
    }
    __shared__ float red[4][4][64];
    red[0][g][lane] = s0;
    red[1][g][lane] = s1;
    red[2][g][lane] = s2;
    red[3][g][lane] = s3;
    __syncthreads();
    if (g == 0) {
        const float* Xt = X + (size_t)(Pn - 2) * H4;   // X[79]
        float zi = Xt[j]          + red[0][0][lane] + red[0][1][lane] + red[0][2][lane] + red[0][3][lane];
        float zf = Xt[j + Hn]     + red[1][0][lane] + red[1][1][lane] + red[1][2][lane] + red[1][3][lane];
        float zg = Xt[j + 2 * Hn] + red[2][0][lane] + red[2][1][lane] + red[2][2][lane] + red[2][3][lane];
        float zo = Xt[j + 3 * Hn] + red[3][0][lane] + red[3][1][lane] + red[3][2][lane] + red[3][3][lane];
        float gi = 1.f / (1.f + __expf(-zi));
        float gf = 1.f / (1.f + __expf(-zf));
        float go = 1.f / (1.f + __expf(-zo));
        float cn = gf * cprev[j] + gi * zg;
        orders[(size_t)(Pn - 1) * Hn + j] = go * cn;
    }
}

// ================= fallback path (ws too small): f32, separate kernels =================
__global__ __launch_bounds__(256) void fb_init_kernel(const float* __restrict__ h0,
                                                      float* __restrict__ h,
                                                      float* __restrict__ c) {
    int i = blockIdx.x * 256 + threadIdx.x;
    h[i] = h0[i];
    c[i] = 0.f;
}

__global__ __launch_bounds__(256) void matvec2_kernel(const float* __restrict__ Wh,
                                                      const float* __restrict__ U,
                                                      const float* __restrict__ h,
                                                      float* __restrict__ zpart) {
    int col4 = blockIdx.x * 256 + threadIdx.x;
    int k0   = blockIdx.y * KC;
    __shared__ float hs[KC];
    if (threadIdx.x < KC) hs[threadIdx.x] = h[k0 + threadIdx.x];
    __syncthreads();
    const float4* W4 = (const float4*)Wh;
    const float4* U4 = (const float4*)U;
    size_t base = (size_t)k0 * (H4 / 4) + col4;
    float4 acc; acc.x = acc.y = acc.z = acc.w = 0.f;
#pragma unroll 2
    for (int k = 0; k < KC; ++k) {
        size_t idx = base + (size_t)k * (H4 / 4);
        float4 w = W4[idx];
        float4 u = U4[idx];
        float hk = hs[k];
        acc.x += hk * (w.x + u.x); acc.y += hk * (w.y + u.y);
        acc.z += hk * (w.z + u.z); acc.w += hk * (w.w + u.w);
    }
    ((float4*)zpart)[(size_t)blockIdx.y * (H4 / 4) + col4] = acc;
}

__global__ __launch_bounds__(256) void gate_kernel(const float* __restrict__ zpart,
                                                   const float* __restrict__ X,
                                                   float* __restrict__ h,
                                                   float* __restrict__ c,
                                                   float* __restrict__ orders,
                                                   int t) {
    int lane = threadIdx.x & 63;
    int g    = threadIdx.x >> 6;
    int j    = blockIdx.x * 64 + lane;
    float s0 = 0.f, s1 = 0.f, s2 = 0.f, s3 = 0.f;
#pragma unroll
    for (int ks = g; ks < KSPLIT; ks += 4) {
        const float* zp = zpart + (size_t)ks * H4;
        s0 += zp[j];
        s1 += zp[j + Hn];
        s2 += zp[j + 2 * Hn];
        s3 += zp[j + 3 * Hn];
    }
    __shared__ float red[4][4][64];
    red[0][g][lane] = s0;
    red[1][g][lane] = s1;
    red[2][g][lane] = s2;
    red[3][g][lane] = s3;
    __syncthreads();
    if (g == 0) {
        const float* Xt = X + (size_t)t * H4;
        float zi = Xt[j]          + red[0][0][lane] + red[0][1][lane] + red[0][2][lane] + red[0][3][lane];
        float zf = Xt[j + Hn]     + red[1][0][lane] + red[1][1][lane] + red[1][2][lane] + red[1][3][lane];
        float zg = Xt[j + 2 * Hn] + red[2][0][lane] + red[2][1][lane] + red[2][2][lane] + red[2][3][lane];
        float zo = Xt[j + 3 * Hn] + red[3][0][lane] + red[3][1][lane] + red[3][2][lane] + red[3][3][lane];
        float gi = 1.f / (1.f + __expf(-zi));
        float gf = 1.f / (1.f + __expf(-zf));
        float go = 1.f / (1.f + __expf(-zo));
        float cn = gf * c[j] + gi * zg;
        float ho = h[j];
        float hn = go * cn;
        orders[(size_t)t * Hn + j] = ho;
        h[j] = hn;
        c[j] = cn;
    }
}

extern "C" void kernel_launch(void* const* d_in, const int* in_sizes, int n_in,
                              void* d_out, int out_size, void* d_ws, size_t ws_size,
                              hipStream_t stream) {
    const float* henc = (const float*)d_in[0];
    const float* h0   = (const float*)d_in[1];
    const float* W    = (const float*)d_in[2];
    const float* U    = (const float*)d_in[3];
    const float* bias = (const float*)d_in[4];
    float* out = (float*)d_out;

    const size_t needM = (size_t)Hn * H4 * sizeof(__half);    // 134 MB fp16 (tiled)
    const size_t needX = (size_t)Pn * H4 * sizeof(float);     // 5.3 MB
    const size_t needZ = (size_t)KSPLIT * H4 * sizeof(float); // 2 MB (x2)
    const size_t needC = (size_t)Hn * sizeof(float);          // 16 KB (x2)

    char* ws = (char*)d_ws;
    const bool fused = ws_size >= needM + needX + 2 * needZ + 2 * needC;

    if (fused) {
        __half* Mt  = (__half*)ws;
        float*  X   = (float*)(ws + needM);
        float*  z0  = (float*)(ws + needM + needX);
        float*  z1  = (float*)(ws + needM + needX + needZ);
        float*  cb0 = (float*)(ws + needM + needX + 2 * needZ);
        float*  cb1 = cb0 + Hn;

        xproj_kernel<<<dim3(H4 / 256, (Pn + TT - 1) / TT), 256, 0, stream>>>(henc, W, bias, X);
        init_kernel<<<dim3(Hn / 256), 256, 0, stream>>>(h0, out, cb0);
        fuse_convert_kernel<<<dim3(CG * 8, KSPLIT), 256, 0, stream>>>(W, U, Mt);

        float* zp[2] = {z0, z1};
        float* cb[2] = {cb0, cb1};
        for (int t = 0; t < Pn - 1; ++t) {   // t streams into zp[t&1]; t=0 uses h0
            step_kernel<<<dim3(CG, KSPLIT), 1024, 0, stream>>>(
                Mt, X, zp[(t + 1) & 1], zp[t & 1],
                cb[(t + 1) & 1], cb[t & 1], out, h0, t);
        }
        // orders[80] from z of t=79 (zp[1]) and c_79 (cb[1])
        final_gate_kernel<<<dim3(Hn / 64), 256, 0, stream>>>(zp[1], X, cb[1], out);
    } else {
        float* X     = (float*)ws;
        float* zpart = (float*)(ws + needX);
        float* h     = (float*)(ws + needX + needZ);
        float* c     = h + Hn;

        xproj_kernel<<<dim3(H4 / 256, (Pn + TT - 1) / TT), 256, 0, stream>>>(henc, W, bias, X);
        fb_init_kernel<<<dim3(Hn / 256), 256, 0, stream>>>(h0, h, c);
        for (int t = 0; t < Pn; ++t) {
            matvec2_kernel<<<dim3(H4 / 4 / 256, KSPLIT), 256, 0, stream>>>(
                W + (size_t)En * H4, U, h, zpart);
            gate_kernel<<<dim3(Hn / 64), 256, 0, stream>>>(zpart, X, h, c, out, t);
        }
    }
}

// Round 11
// 1977.219 us; speedup vs baseline: 9.4217x; 1.0266x over previous
//
#include <hip/hip_runtime.h>
#include <hip/hip_fp16.h>
#include <cstddef>

#define Pn 81
#define En 256
#define Hn 4096
#define H4 16384          // 4*Hn
#define KSPLIT 32
#define KC (Hn / KSPLIT)  // 128 rows per k-chunk
#define CG 8              // column groups: 8 panels x 2048 f32 cols
#define TT 16             // t-tile for X projection

typedef float fx4 __attribute__((ext_vector_type(4)));

// Tiled Mh layout: unit (kc,cgp) owns a contiguous 512KB slice of uint4 (8 halves each).
// uint4 index of (local row k 0..127, col8 0..255) = slice(kc,cgp) + k*256 + col8.
__device__ __forceinline__ size_t mt_slice(int kc, int cgp) {
    return ((size_t)(kc * CG + cgp)) * ((size_t)KC * 256);
}

// ---------------- X[t] = h_enc[t] @ W[:E] + b   (Pn x H4) ----------------
__global__ __launch_bounds__(256) void xproj_kernel(const float* __restrict__ henc,
                                                    const float* __restrict__ W,
                                                    const float* __restrict__ bias,
                                                    float* __restrict__ X) {
    int col = blockIdx.x * 256 + threadIdx.x;
    int t0  = blockIdx.y * TT;
    __shared__ float hs[TT][En];
    for (int r = threadIdx.x; r < TT * En; r += 256) {
        int tt = r >> 8;
        int e  = r & (En - 1);
        hs[tt][e] = (t0 + tt < Pn) ? henc[(size_t)(t0 + tt) * En + e] : 0.f;
    }
    __syncthreads();
    float acc[TT];
    float bc = bias[col];
#pragma unroll
    for (int tt = 0; tt < TT; ++tt) acc[tt] = bc;
    for (int e = 0; e < En; ++e) {
        float w = W[(size_t)e * H4 + col];
#pragma unroll
        for (int tt = 0; tt < TT; ++tt) acc[tt] += hs[tt][e] * w;
    }
    int nt = Pn - t0; if (nt > TT) nt = TT;
    for (int tt = 0; tt < nt; ++tt) X[(size_t)(t0 + tt) * H4 + col] = acc[tt];
}

// ---------------- init: orders[0] = h0, c0 = 0 ----------------
__global__ __launch_bounds__(256) void init_kernel(const float* __restrict__ h0,
                                                   float* __restrict__ orders,
                                                   float* __restrict__ c0) {
    int i = blockIdx.x * 256 + threadIdx.x;
    orders[i] = h0[i];
    c0[i] = 0.f;
}

// ------------- step 0 fused with weight prep: Mt = tiled f16(W[E:]+U); z0 = h0 @ Mf -------
// grid (CG=8, KSPLIT=32), 1024 threads. Block (cgp,kc): rows kc*128..+128 (4 quarter-groups
// of 32 rows), f32 cols cgp*2048..+2048. NT-reads W/U once (single-use streams), emits
// tiled fp16 Mt (cached - steps re-read it 79x) and z0 partials.
__global__ __launch_bounds__(1024) void fuse_step0_kernel(const float* __restrict__ W,
                                                          const float* __restrict__ U,
                                                          const float* __restrict__ h0,
                                                          __half* __restrict__ Mt,
                                                          float* __restrict__ zcur) {
    const int cgp  = blockIdx.x;
    const int kc   = blockIdx.y;
    const int tid  = threadIdx.x;
    const int half = tid >> 8;               // 0..3 (row quarter)
    const int t256 = tid & 255;
    const int c0   = cgp * 2048 + t256 * 8;  // f32 column base (8 per thread)
    uint4* M8 = (uint4*)Mt;
    const size_t slice = mt_slice(kc, cgp);

    __shared__ float hs[KC];
    if (tid < KC) hs[tid] = h0[kc * KC + tid];
    __syncthreads();

    float acc[8];
#pragma unroll
    for (int p = 0; p < 8; ++p) acc[p] = 0.f;

#pragma unroll 4
    for (int k = 0; k < 32; ++k) {
        const int kl   = half * 32 + k;      // local row 0..127
        const int krow = kc * KC + kl;
        const fx4* Wp = (const fx4*)(W + (size_t)(En + krow) * H4 + c0);
        const fx4* Up = (const fx4*)(U + (size_t)krow * H4 + c0);
        fx4 w0 = __builtin_nontemporal_load(&Wp[0]);
        fx4 w1 = __builtin_nontemporal_load(&Wp[1]);
        fx4 u0 = __builtin_nontemporal_load(&Up[0]);
        fx4 u1 = __builtin_nontemporal_load(&Up[1]);
        float m[8];
        m[0] = w0.x + u0.x; m[1] = w0.y + u0.y; m[2] = w0.z + u0.z; m[3] = w0.w + u0.w;
        m[4] = w1.x + u1.x; m[5] = w1.y + u1.y; m[6] = w1.z + u1.z; m[7] = w1.w + u1.w;
        alignas(16) __half2 hm[4];
        hm[0] = __floats2half2_rn(m[0], m[1]);
        hm[1] = __floats2half2_rn(m[2], m[3]);
        hm[2] = __floats2half2_rn(m[4], m[5]);
        hm[3] = __floats2half2_rn(m[6], m[7]);
        M8[slice + (size_t)kl * 256 + t256] = *(const uint4*)hm;
        float hk = hs[kl];
#pragma unroll
        for (int p = 0; p < 8; ++p) acc[p] += hk * m[p];
    }

    __shared__ float accbuf[3][256][9];   // quarters 1..3 park partials (+1 pad)
    if (half != 0) {
#pragma unroll
        for (int p = 0; p < 8; ++p) accbuf[half - 1][t256][p] = acc[p];
    }
    __syncthreads();
    if (half == 0) {
#pragma unroll
        for (int p = 0; p < 8; ++p)
            acc[p] += accbuf[0][t256][p] + accbuf[1][t256][p] + accbuf[2][t256][p];
        float4* zw = (float4*)(zcur + (size_t)kc * H4 + (size_t)c0);
        zw[0] = make_float4(acc[0], acc[1], acc[2], acc[3]);
        zw[1] = make_float4(acc[4], acc[5], acc[6], acc[7]);
    }
}

// ---------------- step t>=1: gate (h_t from zprev) + stream (zcur = h_t @ Mt) ----------
// grid (CG=8, KSPLIT=32), 1024 threads (16 waves/CU).
// Gate: 8 groups x 128 lanes split the 32-slice ks-reduction (64KB/block, 16MB/step).
// Stream: 4 quarter-groups x 256 cols cover the 128-row k-range; 8-deep prefetch; LDS merge.
__global__ __launch_bounds__(1024) void step_kernel(const __half* __restrict__ Mt,
                                                    const float* __restrict__ X,
                                                    const float* __restrict__ zprev,
                                                    float* __restrict__ zcur,
                                                    const float* __restrict__ cprev,
                                                    float* __restrict__ ccur,
                                                    float* __restrict__ orders,
                                                    int t) {
    const int cgp  = blockIdx.x;                 // 0..7
    const int kc   = blockIdx.y;                 // 0..31
    const int tid  = threadIdx.x;
    const int half = tid >> 8;                   // 0..3 (row quarter)
    const int t256 = tid & 255;                  // col8 index
    const uint4* M8 = (const uint4*)Mt;
    const size_t slice = mt_slice(kc, cgp);

    // ---- prefetch first 8 of this thread's 32 row-reads ----
    uint4 buf[8];
#pragma unroll
    for (int p = 0; p < 8; ++p)
        buf[p] = M8[slice + (size_t)(half * 32 + p) * 256 + t256];

    __shared__ float hs[KC];
    {
        const int lane = tid & 127;              // row within chunk
        const int g    = tid >> 7;               // 0..7
        const int j    = kc * KC + lane;
        float s0 = 0.f, s1 = 0.f, s2 = 0.f, s3 = 0.f;
#pragma unroll
        for (int ks = g; ks < KSPLIT; ks += 8) {
            const float* zpp = zprev + (size_t)ks * H4;
            s0 += zpp[j];
            s1 += zpp[j + Hn];
            s2 += zpp[j + 2 * Hn];
            s3 += zpp[j + 3 * Hn];
        }
        __shared__ float red[4][8][KC];
        red[0][g][lane] = s0;
        red[1][g][lane] = s1;
        red[2][g][lane] = s2;
        red[3][g][lane] = s3;
        __syncthreads();
        if (g == 0) {
            const float* Xt = X + (size_t)(t - 1) * H4;
            float zi = Xt[j], zf = Xt[j + Hn], zg = Xt[j + 2 * Hn], zo = Xt[j + 3 * Hn];
#pragma unroll
            for (int g2 = 0; g2 < 8; ++g2) {
                zi += red[0][g2][lane];
                zf += red[1][g2][lane];
                zg += red[2][g2][lane];
                zo += red[3][g2][lane];
            }
            float gi = 1.f / (1.f + __expf(-zi));
            float gf = 1.f / (1.f + __expf(-zf));
            float go = 1.f / (1.f + __expf(-zo));
            float cn = gf * cprev[j] + gi * zg;   // candidate activation = identity
            float hn = go * cn;                   // output activation = identity
            if (cgp == 0) {
                orders[(size_t)t * Hn + j] = hn;  // orders[t] = h_t
                ccur[j] = cn;
            }
            hs[lane] = hn;
        }
    }
    __syncthreads();

    // ---- stream: zcur[kc][cgp cols] over this block's 128-row chunk ----
    float acc[8];
#pragma unroll
    for (int p = 0; p < 8; ++p) acc[p] = 0.f;
#pragma unroll
    for (int k = 0; k < 32; ++k) {
        uint4 raw;
        if (k < 8) raw = buf[k];
        else       raw = M8[slice + (size_t)(half * 32 + k) * 256 + t256];
        float hk = hs[half * 32 + k];
        const __half2* hp = (const __half2*)&raw;
#pragma unroll
        for (int q = 0; q < 4; ++q) {
            float2 f = __half22float2(hp[q]);
            acc[2 * q]     += hk * f.x;
            acc[2 * q + 1] += hk * f.y;
        }
    }
    __shared__ float accbuf[3][256][9];   // quarters 1..3 park partials (+1 pad)
    if (half != 0) {
#pragma unroll
        for (int p = 0; p < 8; ++p) accbuf[half - 1][t256][p] = acc[p];
    }
    __syncthreads();
    if (half == 0) {
#pragma unroll
        for (int p = 0; p < 8; ++p)
            acc[p] += accbuf[0][t256][p] + accbuf[1][t256][p] + accbuf[2][t256][p];
        float4* zw = (float4*)(zcur + (size_t)kc * H4 + (size_t)(cgp * 256 + t256) * 8);
        zw[0] = make_float4(acc[0], acc[1], acc[2], acc[3]);
        zw[1] = make_float4(acc[4], acc[5], acc[6], acc[7]);
    }
}

// ---------------- epilogue: orders[80] = h_80 (gate only, no matvec) ----------------
__global__ __launch_bounds__(256) void final_gate_kernel(const float* __restrict__ zprev,
                                                         const float* __restrict__ X,
                                                         const float* __restrict__ cprev,
                                                         float* __restrict__ orders) {
    const int lane = threadIdx.x & 63;
    const int g    = threadIdx.x >> 6;           // 0..3
    const int j    = blockIdx.x * 64 + lane;
    float s0 = 0.f, s1 = 0.f, s2 = 0.f, s3 = 0.f;
#pragma unroll
    for (int ks = g; ks < KSPLIT; ks += 4) {
        const float* zp = zprev + (size_t)ks * H4;
        s0 += zp[j];
        s1 += zp[j + Hn];
        s2 += zp[j + 2 * Hn];
        s3 += zp[j + 3 * Hn];
    }
    __shared__ float red[4][4][64];
    red[0][g][lane] = s0;
    red[1][g][lane] = s1;
    red[2][g][lane] = s2;
    red[3][g][lane] = s3;
    __syncthreads();
    if (g == 0) {
        const float* Xt = X + (size_t)(Pn - 2) * H4;   // X[79]
        float zi = Xt[j]          + red[0][0][lane] + red[0][1][lane] + red[0][2][lane] + red[0][3][lane];
        float zf = Xt[j + Hn]     + red[1][0][lane] + red[1][1][lane] + red[1][2][lane] + red[1][3][lane];
        float zg = Xt[j + 2 * Hn] + red[2][0][lane] + red[2][1][lane] + red[2][2][lane] + red[2][3][lane];
        float zo = Xt[j + 3 * Hn] + red[3][0][lane] + red[3][1][lane] + red[3][2][lane] + red[3][3][lane];
        float gi = 1.f / (1.f + __expf(-zi));
        float gf = 1.f / (1.f + __expf(-zf));
        float go = 1.f / (1.f + __expf(-zo));
        float cn = gf * cprev[j] + gi * zg;
        orders[(size_t)(Pn - 1) * Hn + j] = go * cn;
    }
}

// ================= fallback path (ws too small): f32, separate kernels =================
__global__ __launch_bounds__(256) void fb_init_kernel(const float* __restrict__ h0,
                                                      float* __restrict__ h,
                                                      float* __restrict__ c) {
    int i = blockIdx.x * 256 + threadIdx.x;
    h[i] = h0[i];
    c[i] = 0.f;
}

__global__ __launch_bounds__(256) void matvec2_kernel(const float* __restrict__ Wh,
                                                      const float* __restrict__ U,
                                                      const float* __restrict__ h,
                                                      float* __restrict__ zpart) {
    int col4 = blockIdx.x * 256 + threadIdx.x;
    int k0   = blockIdx.y * KC;
    __shared__ float hs[KC];
    if (threadIdx.x < KC) hs[threadIdx.x] = h[k0 + threadIdx.x];
    __syncthreads();
    const float4* W4 = (const float4*)Wh;
    const float4* U4 = (const float4*)U;
    size_t base = (size_t)k0 * (H4 / 4) + col4;
    float4 acc; acc.x = acc.y = acc.z = acc.w = 0.f;
#pragma unroll 2
    for (int k = 0; k < KC; ++k) {
        size_t idx = base + (size_t)k * (H4 / 4);
        float4 w = W4[idx];
        float4 u = U4[idx];
        float hk = hs[k];
        acc.x += hk * (w.x + u.x); acc.y += hk * (w.y + u.y);
        acc.z += hk * (w.z + u.z); acc.w += hk * (w.w + u.w);
    }
    ((float4*)zpart)[(size_t)blockIdx.y * (H4 / 4) + col4] = acc;
}

__global__ __launch_bounds__(256) void gate_kernel(const float* __restrict__ zpart,
                                                   const float* __restrict__ X,
                                                   float* __restrict__ h,
                                                   float* __restrict__ c,
                                                   float* __restrict__ orders,
                                                   int t) {
    int lane = threadIdx.x & 63;
    int g    = threadIdx.x >> 6;
    int j    = blockIdx.x * 64 + lane;
    float s0 = 0.f, s1 = 0.f, s2 = 0.f, s3 = 0.f;
#pragma unroll
    for (int ks = g; ks < KSPLIT; ks += 4) {
        const float* zp = zpart + (size_t)ks * H4;
        s0 += zp[j];
        s1 += zp[j + Hn];
        s2 += zp[j + 2 * Hn];
        s3 += zp[j + 3 * Hn];
    }
    __shared__ float red[4][4][64];
    red[0][g][lane] = s0;
    red[1][g][lane] = s1;
    red[2][g][lane] = s2;
    red[3][g][lane] = s3;
    __syncthreads();
    if (g == 0) {
        const float* Xt = X + (size_t)t * H4;
        float zi = Xt[j]          + red[0][0][lane] + red[0][1][lane] + red[0][2][lane] + red[0][3][lane];
        float zf = Xt[j + Hn]     + red[1][0][lane] + red[1][1][lane] + red[1][2][lane] + red[1][3][lane];
        float zg = Xt[j + 2 * Hn] + red[2][0][lane] + red[2][1][lane] + red[2][2][lane] + red[2][3][lane];
        float zo = Xt[j + 3 * Hn] + red[3][0][lane] + red[3][1][lane] + red[3][2][lane] + red[3][3][lane];
        float gi = 1.f / (1.f + __expf(-zi));
        float gf = 1.f / (1.f + __expf(-zf));
        float go = 1.f / (1.f + __expf(-zo));
        float cn = gf * c[j] + gi * zg;
        float ho = h[j];
        float hn = go * cn;
        orders[(size_t)t * Hn + j] = ho;
        h[j] = hn;
        c[j] = cn;
    }
}

extern "C" void kernel_launch(void* const* d_in, const int* in_sizes, int n_in,
                              void* d_out, int out_size, void* d_ws, size_t ws_size,
                              hipStream_t stream) {
    const float* henc = (const float*)d_in[0];
    const float* h0   = (const float*)d_in[1];
    const float* W    = (const float*)d_in[2];
    const float* U    = (const float*)d_in[3];
    const float* bias = (const float*)d_in[4];
    float* out = (float*)d_out;

    const size_t needM = (size_t)Hn * H4 * sizeof(__half);    // 134 MB fp16 (tiled)
    const size_t needX = (size_t)Pn * H4 * sizeof(float);     // 5.3 MB
    const size_t needZ = (size_t)KSPLIT * H4 * sizeof(float); // 2 MB (x2)
    const size_t needC = (size_t)Hn * sizeof(float);          // 16 KB (x2)

    char* ws = (char*)d_ws;
    const bool fused = ws_size >= needM + needX + 2 * needZ + 2 * needC;

    if (fused) {
        __half* Mt  = (__half*)ws;
        float*  X   = (float*)(ws + needM);
        float*  z0  = (float*)(ws + needM + needX);
        float*  z1  = (float*)(ws + needM + needX + needZ);
        float*  cb0 = (float*)(ws + needM + needX + 2 * needZ);
        float*  cb1 = cb0 + Hn;

        xproj_kernel<<<dim3(H4 / 256, (Pn + TT - 1) / TT), 256, 0, stream>>>(henc, W, bias, X);
        init_kernel<<<dim3(Hn / 256), 256, 0, stream>>>(h0, out, cb0);
        // step 0 fused with weight prep: writes Mt and z0 (= zp[0])
        fuse_step0_kernel<<<dim3(CG, KSPLIT), 1024, 0, stream>>>(W, U, h0, Mt, z0);

        float* zp[2] = {z0, z1};
        float* cb[2] = {cb0, cb1};
        for (int t = 1; t < Pn - 1; ++t) {   // steps 1..79: stream into zp[t&1]
            step_kernel<<<dim3(CG, KSPLIT), 1024, 0, stream>>>(
                Mt, X, zp[(t + 1) & 1], zp[t & 1],
                cb[(t + 1) & 1], cb[t & 1], out, t);
        }
        // orders[80] from z of t=79 (zp[1]) and c_79 (cb[1])
        final_gate_kernel<<<dim3(Hn / 64), 256, 0, stream>>>(zp[1], X, cb[1], out);
    } else {
        float* X     = (float*)ws;
        float* zpart = (float*)(ws + needX);
        float* h     = (float*)(ws + needX + needZ);
        float* c     = h + Hn;

        xproj_kernel<<<dim3(H4 / 256, (Pn + TT - 1) / TT), 256, 0, stream>>>(henc, W, bias, X);
        fb_init_kernel<<<dim3(Hn / 256), 256, 0, stream>>>(h0, h, c);
        for (int t = 0; t < Pn; ++t) {
            matvec2_kernel<<<dim3(H4 / 4 / 256, KSPLIT), 256, 0, stream>>>(
                W + (size_t)En * H4, U, h, zpart);
            gate_kernel<<<dim3(Hn / 64), 256, 0, stream>>>(zpart, X, h, c, out, t);
        }
    }
}